// Round 1
// baseline (10489.663 us; speedup 1.0000x reference)
//
#include <hip/hip_runtime.h>
#include <cstdint>
#include <cstddef>

// ---------------------------------------------------------------------------
// GIN forward: enc MLP -> scatter-add (GINConv agg) -> conv MLP (+residual)
//              -> dec MLP.  All fp32 (round-0 correctness baseline).
// Shapes: N=100000 nodes, E=1.6M edges, IN=128, HID=256, MLP_H=512, OUT=128.
// ---------------------------------------------------------------------------

#define GBM 128
#define GBN 128
#define GBK 16

// C[M,N] = act(A(+A2) @ W + bias) (+Res).  W row-major [K,N].
// Tile 128x128, 256 threads, 8x8 micro-tile per thread (split 4+4 halves for
// fully coalesced float4 loads/stores and conflict-free LDS reads).
template<bool RELU, bool HAS_A2, bool HAS_RES>
__global__ __launch_bounds__(256, 2)
void gemm_kernel(const float* __restrict__ A, const float* __restrict__ A2,
                 const float* __restrict__ W, const float* __restrict__ Bias,
                 const float* __restrict__ Res, float* __restrict__ C,
                 int M, int K, int N)
{
    __shared__ float As[GBK][GBM + 4];   // As[k][m]  (+4 pad: conflict-free)
    __shared__ float Ws[GBK][GBN + 4];   // Ws[k][n]

    const int tid = threadIdx.x;
    const int m0 = blockIdx.x * GBM;
    const int n0 = blockIdx.y * GBN;

    const int tx = tid & 15;   // n micro index
    const int ty = tid >> 4;   // m micro index

    float acc[8][8];
#pragma unroll
    for (int i = 0; i < 8; ++i)
#pragma unroll
        for (int j = 0; j < 8; ++j) acc[i][j] = 0.f;

    // A-tile load mapping: 128 rows x 16 k, float4 per thread, 2 passes
    const int a_row = tid >> 2;          // 0..63
    const int a_k4  = (tid & 3) << 2;    // 0,4,8,12
    // W-tile load mapping: 16 k-rows x 128 n, float4 per thread, 2 passes
    const int w_kk  = tid >> 5;          // 0..7
    const int w_n4  = (tid & 31) << 2;   // 0..124

    for (int k0 = 0; k0 < K; k0 += GBK) {
#pragma unroll
        for (int it = 0; it < 2; ++it) {
            const int m  = a_row + it * 64;
            const int gm = m0 + m;
            float4 v = make_float4(0.f, 0.f, 0.f, 0.f);
            if (gm < M) {
                v = *reinterpret_cast<const float4*>(&A[(size_t)gm * K + k0 + a_k4]);
                if (HAS_A2) {
                    const float4 v2 = *reinterpret_cast<const float4*>(&A2[(size_t)gm * K + k0 + a_k4]);
                    v.x += v2.x; v.y += v2.y; v.z += v2.z; v.w += v2.w;
                }
            }
            As[a_k4 + 0][m] = v.x;
            As[a_k4 + 1][m] = v.y;
            As[a_k4 + 2][m] = v.z;
            As[a_k4 + 3][m] = v.w;
        }
#pragma unroll
        for (int it = 0; it < 2; ++it) {
            const int kk = w_kk + it * 8;
            const float4 v = *reinterpret_cast<const float4*>(&W[(size_t)(k0 + kk) * N + n0 + w_n4]);
            *reinterpret_cast<float4*>(&Ws[kk][w_n4]) = v;
        }
        __syncthreads();

#pragma unroll
        for (int kk = 0; kk < GBK; ++kk) {
            const float4 a0 = *reinterpret_cast<const float4*>(&As[kk][ty * 4]);
            const float4 a1 = *reinterpret_cast<const float4*>(&As[kk][64 + ty * 4]);
            const float4 b0 = *reinterpret_cast<const float4*>(&Ws[kk][tx * 4]);
            const float4 b1 = *reinterpret_cast<const float4*>(&Ws[kk][64 + tx * 4]);
            const float a[8] = {a0.x, a0.y, a0.z, a0.w, a1.x, a1.y, a1.z, a1.w};
            const float b[8] = {b0.x, b0.y, b0.z, b0.w, b1.x, b1.y, b1.z, b1.w};
#pragma unroll
            for (int i = 0; i < 8; ++i)
#pragma unroll
                for (int j = 0; j < 8; ++j)
                    acc[i][j] = __builtin_fmaf(a[i], b[j], acc[i][j]);
        }
        __syncthreads();
    }

    // epilogue: bias (+relu) (+residual), coalesced float4 stores
#pragma unroll
    for (int ih = 0; ih < 2; ++ih) {
#pragma unroll
        for (int i = 0; i < 4; ++i) {
            const int row = m0 + ih * 64 + ty * 4 + i;
            if (row >= M) continue;
#pragma unroll
            for (int jh = 0; jh < 2; ++jh) {
                const int col = n0 + jh * 64 + tx * 4;
                float r[4];
#pragma unroll
                for (int j = 0; j < 4; ++j) {
                    r[j] = acc[ih * 4 + i][jh * 4 + j] + Bias[col + j];
                    if (RELU) r[j] = fmaxf(r[j], 0.f);
                }
                if (HAS_RES) {
                    const float4 rv = *reinterpret_cast<const float4*>(&Res[(size_t)row * N + col]);
                    r[0] += rv.x; r[1] += rv.y; r[2] += rv.z; r[3] += rv.w;
                }
                float4 o; o.x = r[0]; o.y = r[1]; o.z = r[2]; o.w = r[3];
                *reinterpret_cast<float4*>(&C[(size_t)row * N + col]) = o;
            }
        }
    }
}

__global__ __launch_bounds__(256)
void zero_kernel(float4* __restrict__ p, int n4)
{
    const int i = blockIdx.x * 256 + threadIdx.x;
    if (i < n4) p[i] = make_float4(0.f, 0.f, 0.f, 0.f);
}

// one wave (64 lanes) per edge: lane l handles channels 4l..4l+3 of HID=256
__global__ __launch_bounds__(256)
void scatter_kernel(const float* __restrict__ h, const int* __restrict__ ei,
                    float* __restrict__ agg, int E)
{
    const int wave = (int)((blockIdx.x * 256 + threadIdx.x) >> 6);
    const int lane = threadIdx.x & 63;
    if (wave >= E) return;
    const int src = ei[wave];        // edge_index[0][e]
    const int dst = ei[E + wave];    // edge_index[1][e]
    const float4 v = *reinterpret_cast<const float4*>(&h[(size_t)src * 256 + lane * 4]);
    float* p = &agg[(size_t)dst * 256 + lane * 4];
    atomicAdd(p + 0, v.x);
    atomicAdd(p + 1, v.y);
    atomicAdd(p + 2, v.z);
    atomicAdd(p + 3, v.w);
}

extern "C" void kernel_launch(void* const* d_in, const int* in_sizes, int n_in,
                              void* d_out, int out_size, void* d_ws, size_t ws_size,
                              hipStream_t stream)
{
    const float* x   = (const float*)d_in[0];
    const int*   ei  = (const int*)d_in[1];   // int32 (JAX x64 disabled)
    // d_in[2] = iterations (unused, always 1 pass)
    const float* enc_w1 = (const float*)d_in[3];
    const float* enc_b1 = (const float*)d_in[4];
    const float* enc_w2 = (const float*)d_in[5];
    const float* enc_b2 = (const float*)d_in[6];
    const float* enc_w3 = (const float*)d_in[7];
    const float* enc_b3 = (const float*)d_in[8];
    const float* conv_w1 = (const float*)d_in[9];
    const float* conv_b1 = (const float*)d_in[10];
    const float* conv_w2 = (const float*)d_in[11];
    const float* conv_b2 = (const float*)d_in[12];
    const float* conv_w3 = (const float*)d_in[13];
    const float* conv_b3 = (const float*)d_in[14];
    const float* dec_w1 = (const float*)d_in[15];
    const float* dec_b1 = (const float*)d_in[16];
    const float* dec_w2 = (const float*)d_in[17];
    const float* dec_b2 = (const float*)d_in[18];
    const float* dec_w3 = (const float*)d_in[19];
    const float* dec_b3 = (const float*)d_in[20];
    float* out = (float*)d_out;

    const int M = 100000;
    const int E = 1600000;
    const size_t HN = (size_t)M * 256;       // 25.6M floats

    // workspace layout: h[M,256] | g[M,256] (agg, then h2) | t1 | t2
    float* h  = (float*)d_ws;
    float* g  = h + HN;
    float* t1 = g + HN;

    // adaptive chunking over M so t1/t2 (512-wide) fit whatever ws remains
    const size_t fixed = 2 * HN * 4;                    // h + g bytes
    size_t remain = (ws_size > fixed) ? ws_size - fixed : 0;
    long long ch = (long long)(remain / (2 * 512 * 4)); // rows for t1+t2
    if (ch > M) ch = M;
    ch &= ~127LL;
    if (ch < 128) ch = 128;                             // last-resort floor
    const int CH = (int)ch;
    float* t2 = t1 + (size_t)CH * 512;

    const dim3 blk(256);
    auto mtiles = [](int m) { return (m + GBM - 1) / GBM; };

    // ---- encoder: x ->(relu) t1 ->(relu) t2 ->(relu) h ----
    for (int m0 = 0; m0 < M; m0 += CH) {
        const int cm = (M - m0 < CH) ? (M - m0) : CH;
        gemm_kernel<true, false, false><<<dim3(mtiles(cm), 4), blk, 0, stream>>>(
            x + (size_t)m0 * 128, nullptr, enc_w1, enc_b1, nullptr, t1, cm, 128, 512);
        gemm_kernel<true, false, false><<<dim3(mtiles(cm), 4), blk, 0, stream>>>(
            t1, nullptr, enc_w2, enc_b2, nullptr, t2, cm, 512, 512);
        gemm_kernel<true, false, false><<<dim3(mtiles(cm), 2), blk, 0, stream>>>(
            t2, nullptr, enc_w3, enc_b3, nullptr, h + (size_t)m0 * 256, cm, 512, 256);
    }

    // ---- GINConv aggregation: g[dst] += h[src] ----
    zero_kernel<<<(int)((HN / 4 + 255) / 256), blk, 0, stream>>>((float4*)g, (int)(HN / 4));
    scatter_kernel<<<(E + 3) / 4, blk, 0, stream>>>(h, ei, g, E);

    // ---- conv MLP with input add (h+g) and output residual (h + relu(...)) ----
    for (int m0 = 0; m0 < M; m0 += CH) {
        const int cm = (M - m0 < CH) ? (M - m0) : CH;
        gemm_kernel<true, true, false><<<dim3(mtiles(cm), 4), blk, 0, stream>>>(
            h + (size_t)m0 * 256, g + (size_t)m0 * 256, conv_w1, conv_b1, nullptr, t1, cm, 256, 512);
        gemm_kernel<true, false, false><<<dim3(mtiles(cm), 4), blk, 0, stream>>>(
            t1, nullptr, conv_w2, conv_b2, nullptr, t2, cm, 512, 512);
        gemm_kernel<true, false, true><<<dim3(mtiles(cm), 2), blk, 0, stream>>>(
            t2, nullptr, conv_w3, conv_b3, h + (size_t)m0 * 256, g + (size_t)m0 * 256, cm, 512, 256);
    }

    // ---- decoder: g ->(relu) t1 ->(relu) t2 -> out (no last act) ----
    for (int m0 = 0; m0 < M; m0 += CH) {
        const int cm = (M - m0 < CH) ? (M - m0) : CH;
        gemm_kernel<true, false, false><<<dim3(mtiles(cm), 4), blk, 0, stream>>>(
            g + (size_t)m0 * 256, nullptr, dec_w1, dec_b1, nullptr, t1, cm, 256, 512);
        gemm_kernel<true, false, false><<<dim3(mtiles(cm), 4), blk, 0, stream>>>(
            t1, nullptr, dec_w2, dec_b2, nullptr, t2, cm, 512, 512);
        gemm_kernel<false, false, false><<<dim3(mtiles(cm), 1), blk, 0, stream>>>(
            t2, nullptr, dec_w3, dec_b3, nullptr, out + (size_t)m0 * 128, cm, 512, 128);
    }
}

// Round 2
// 5745.177 us; speedup vs baseline: 1.8258x; 1.8258x over previous
//
#include <hip/hip_runtime.h>
#include <cstdint>
#include <cstddef>

// ---------------------------------------------------------------------------
// GIN forward: enc MLP -> CSR-sorted gather aggregation -> conv MLP(+residual)
//              -> dec MLP.  fp32 GEMMs (round-2: atomic-free aggregation).
// N=100000 nodes, E=1.6M edges, IN=128, HID=256, MLP_H=512, OUT=128.
// ---------------------------------------------------------------------------

#define GBM 128
#define GBN 128
#define GBK 16

template<bool RELU, bool HAS_RES>
__global__ __launch_bounds__(256, 2)
void gemm_kernel(const float* __restrict__ A,
                 const float* __restrict__ W, const float* __restrict__ Bias,
                 const float* __restrict__ Res, float* __restrict__ C,
                 int M, int K, int N)
{
    __shared__ float As[GBK][GBM + 4];
    __shared__ float Ws[GBK][GBN + 4];

    const int tid = threadIdx.x;
    const int m0 = blockIdx.x * GBM;
    const int n0 = blockIdx.y * GBN;
    const int tx = tid & 15;
    const int ty = tid >> 4;

    float acc[8][8];
#pragma unroll
    for (int i = 0; i < 8; ++i)
#pragma unroll
        for (int j = 0; j < 8; ++j) acc[i][j] = 0.f;

    const int a_row = tid >> 2;
    const int a_k4  = (tid & 3) << 2;
    const int w_kk  = tid >> 5;
    const int w_n4  = (tid & 31) << 2;

    for (int k0 = 0; k0 < K; k0 += GBK) {
#pragma unroll
        for (int it = 0; it < 2; ++it) {
            const int m  = a_row + it * 64;
            const int gm = m0 + m;
            float4 v = make_float4(0.f, 0.f, 0.f, 0.f);
            if (gm < M)
                v = *reinterpret_cast<const float4*>(&A[(size_t)gm * K + k0 + a_k4]);
            As[a_k4 + 0][m] = v.x;
            As[a_k4 + 1][m] = v.y;
            As[a_k4 + 2][m] = v.z;
            As[a_k4 + 3][m] = v.w;
        }
#pragma unroll
        for (int it = 0; it < 2; ++it) {
            const int kk = w_kk + it * 8;
            const float4 v = *reinterpret_cast<const float4*>(&W[(size_t)(k0 + kk) * N + n0 + w_n4]);
            *reinterpret_cast<float4*>(&Ws[kk][w_n4]) = v;
        }
        __syncthreads();

#pragma unroll
        for (int kk = 0; kk < GBK; ++kk) {
            const float4 a0 = *reinterpret_cast<const float4*>(&As[kk][ty * 4]);
            const float4 a1 = *reinterpret_cast<const float4*>(&As[kk][64 + ty * 4]);
            const float4 b0 = *reinterpret_cast<const float4*>(&Ws[kk][tx * 4]);
            const float4 b1 = *reinterpret_cast<const float4*>(&Ws[kk][64 + tx * 4]);
            const float a[8] = {a0.x, a0.y, a0.z, a0.w, a1.x, a1.y, a1.z, a1.w};
            const float b[8] = {b0.x, b0.y, b0.z, b0.w, b1.x, b1.y, b1.z, b1.w};
#pragma unroll
            for (int i = 0; i < 8; ++i)
#pragma unroll
                for (int j = 0; j < 8; ++j)
                    acc[i][j] = __builtin_fmaf(a[i], b[j], acc[i][j]);
        }
        __syncthreads();
    }

#pragma unroll
    for (int ih = 0; ih < 2; ++ih) {
#pragma unroll
        for (int i = 0; i < 4; ++i) {
            const int row = m0 + ih * 64 + ty * 4 + i;
            if (row >= M) continue;
#pragma unroll
            for (int jh = 0; jh < 2; ++jh) {
                const int col = n0 + jh * 64 + tx * 4;
                float r[4];
#pragma unroll
                for (int j = 0; j < 4; ++j) {
                    r[j] = acc[ih * 4 + i][jh * 4 + j] + Bias[col + j];
                    if (RELU) r[j] = fmaxf(r[j], 0.f);
                }
                if (HAS_RES) {
                    const float4 rv = *reinterpret_cast<const float4*>(&Res[(size_t)row * N + col]);
                    r[0] += rv.x; r[1] += rv.y; r[2] += rv.z; r[3] += rv.w;
                }
                float4 o; o.x = r[0]; o.y = r[1]; o.z = r[2]; o.w = r[3];
                *reinterpret_cast<float4*>(&C[(size_t)row * N + col]) = o;
            }
        }
    }
}

// ------------------------- CSR build (counting sort) ------------------------

__global__ __launch_bounds__(256)
void zero_ints(int* __restrict__ p, int n)
{
    const int i = blockIdx.x * 256 + threadIdx.x;
    if (i < n) p[i] = 0;
}

__global__ __launch_bounds__(256)
void hist_kernel(const int* __restrict__ ei, int* __restrict__ cnt, int E)
{
    const int e = blockIdx.x * 256 + threadIdx.x;
    if (e < E) atomicAdd(&cnt[ei[E + e]], 1);   // dst
}

__global__ __launch_bounds__(256)
void scan_reduce(const int* __restrict__ cnt, int* __restrict__ bsum, int N)
{
    __shared__ int s[256];
    const int i = blockIdx.x * 256 + threadIdx.x;
    s[threadIdx.x] = (i < N) ? cnt[i] : 0;
    __syncthreads();
#pragma unroll
    for (int off = 128; off > 0; off >>= 1) {
        if (threadIdx.x < off) s[threadIdx.x] += s[threadIdx.x + off];
        __syncthreads();
    }
    if (threadIdx.x == 0) bsum[blockIdx.x] = s[0];
}

__global__ __launch_bounds__(512)
void scan_blocksums(int* __restrict__ bsum, int NB)   // single block, NB <= 512
{
    __shared__ int a[512], b[512];
    const int t = threadIdx.x;
    const int v = (t < NB) ? bsum[t] : 0;
    a[t] = v;
    __syncthreads();
    int* s = a; int* d = b;
    for (int off = 1; off < 512; off <<= 1) {
        int x = s[t];
        if (t >= off) x += s[t - off];
        d[t] = x;
        __syncthreads();
        int* tmp = s; s = d; d = tmp;
    }
    if (t < NB) bsum[t] = s[t] - v;   // exclusive
}

__global__ __launch_bounds__(256)
void scan_final(const int* __restrict__ cnt, const int* __restrict__ bpre,
                int* __restrict__ off, int* __restrict__ cur, int N)
{
    __shared__ int a[256], b[256];
    const int i = blockIdx.x * 256 + threadIdx.x;
    const int t = threadIdx.x;
    const int v = (i < N) ? cnt[i] : 0;
    a[t] = v;
    __syncthreads();
    int* s = a; int* d = b;
    for (int o = 1; o < 256; o <<= 1) {
        int x = s[t];
        if (t >= o) x += s[t - o];
        d[t] = x;
        __syncthreads();
        int* tmp = s; s = d; d = tmp;
    }
    const int excl = s[t] - v + bpre[blockIdx.x];
    if (i < N) {
        off[i] = excl;
        cur[i] = excl;
        if (i == N - 1) off[N] = excl + v;
    }
}

__global__ __launch_bounds__(256)
void order_kernel(const int* __restrict__ ei, int* __restrict__ cur,
                  int* __restrict__ ssrc, int E)
{
    const int e = blockIdx.x * 256 + threadIdx.x;
    if (e >= E) return;
    const int s = ei[e];
    const int d = ei[E + e];
    const int pos = atomicAdd(&cur[d], 1);
    ssrc[pos] = s;
}

// one wave per node: hpg[i] = h[i] + sum_{e in CSR[i]} h[ssrc[e]]
__global__ __launch_bounds__(256)
void agg_kernel(const float* __restrict__ h, const int* __restrict__ off,
                const int* __restrict__ ssrc, float* __restrict__ hpg, int N)
{
    const int wid  = (int)((blockIdx.x * 256 + threadIdx.x) >> 6);
    const int lane = threadIdx.x & 63;
    if (wid >= N) return;
    const int e0 = off[wid];
    const int e1 = off[wid + 1];

    float4 acc = reinterpret_cast<const float4*>(&h[(size_t)wid * 256])[lane];

    int e = e0;
    // 2-way unrolled for load ILP
    for (; e + 1 < e1; e += 2) {
        const int s0 = ssrc[e];
        const int s1 = ssrc[e + 1];
        const float4 v0 = reinterpret_cast<const float4*>(&h[(size_t)s0 * 256])[lane];
        const float4 v1 = reinterpret_cast<const float4*>(&h[(size_t)s1 * 256])[lane];
        acc.x += v0.x + v1.x; acc.y += v0.y + v1.y;
        acc.z += v0.z + v1.z; acc.w += v0.w + v1.w;
    }
    if (e < e1) {
        const int s0 = ssrc[e];
        const float4 v0 = reinterpret_cast<const float4*>(&h[(size_t)s0 * 256])[lane];
        acc.x += v0.x; acc.y += v0.y; acc.z += v0.z; acc.w += v0.w;
    }
    reinterpret_cast<float4*>(&hpg[(size_t)wid * 256])[lane] = acc;
}

// ---------------------------------------------------------------------------

extern "C" void kernel_launch(void* const* d_in, const int* in_sizes, int n_in,
                              void* d_out, int out_size, void* d_ws, size_t ws_size,
                              hipStream_t stream)
{
    const float* x   = (const float*)d_in[0];
    const int*   ei  = (const int*)d_in[1];
    const float* enc_w1 = (const float*)d_in[3];
    const float* enc_b1 = (const float*)d_in[4];
    const float* enc_w2 = (const float*)d_in[5];
    const float* enc_b2 = (const float*)d_in[6];
    const float* enc_w3 = (const float*)d_in[7];
    const float* enc_b3 = (const float*)d_in[8];
    const float* conv_w1 = (const float*)d_in[9];
    const float* conv_b1 = (const float*)d_in[10];
    const float* conv_w2 = (const float*)d_in[11];
    const float* conv_b2 = (const float*)d_in[12];
    const float* conv_w3 = (const float*)d_in[13];
    const float* conv_b3 = (const float*)d_in[14];
    const float* dec_w1 = (const float*)d_in[15];
    const float* dec_b1 = (const float*)d_in[16];
    const float* dec_w2 = (const float*)d_in[17];
    const float* dec_b2 = (const float*)d_in[18];
    const float* dec_w3 = (const float*)d_in[19];
    const float* dec_b3 = (const float*)d_in[20];
    float* out = (float*)d_out;

    const int M = 100000;
    const int E = 1600000;
    const size_t HN = (size_t)M * 256;

    // workspace: h[HN] | hpg[HN] | cnt[100000] off[100004] cur[100000]
    //            bsum[512] ssrc[E] | t1 | t2
    float* h   = (float*)d_ws;
    float* hpg = h + HN;
    int* cnt  = (int*)(hpg + HN);
    int* off  = cnt + 100000;
    int* cur  = off + 100004;
    int* bsum = cur + 100000;
    int* ssrc = bsum + 512;
    float* t1 = (float*)(ssrc + E);

    const size_t fixed = (2 * HN + (100000 + 100004 + 100000 + 512 + (size_t)E)) * 4;
    size_t remain = (ws_size > fixed) ? ws_size - fixed : 0;
    long long ch = (long long)(remain / (2 * 512 * 4));
    if (ch > M) ch = M;
    ch &= ~127LL;
    if (ch < 128) ch = 128;
    const int CH = (int)ch;
    float* t2 = t1 + (size_t)CH * 512;

    const dim3 blk(256);
    auto mtiles = [](int m) { return (m + GBM - 1) / GBM; };
    const int NB = (M + 255) / 256;   // 391

    // ---- encoder: x ->(relu) t1 ->(relu) t2 ->(relu) h ----
    for (int m0 = 0; m0 < M; m0 += CH) {
        const int cm = (M - m0 < CH) ? (M - m0) : CH;
        gemm_kernel<true, false><<<dim3(mtiles(cm), 4), blk, 0, stream>>>(
            x + (size_t)m0 * 128, enc_w1, enc_b1, nullptr, t1, cm, 128, 512);
        gemm_kernel<true, false><<<dim3(mtiles(cm), 4), blk, 0, stream>>>(
            t1, enc_w2, enc_b2, nullptr, t2, cm, 512, 512);
        gemm_kernel<true, false><<<dim3(mtiles(cm), 2), blk, 0, stream>>>(
            t2, enc_w3, enc_b3, nullptr, h + (size_t)m0 * 256, cm, 512, 256);
    }

    // ---- CSR build + gather aggregation: hpg = h + scatter_sum(h) ----
    zero_ints<<<(M + 255) / 256, blk, 0, stream>>>(cnt, M);
    hist_kernel<<<(E + 255) / 256, blk, 0, stream>>>(ei, cnt, E);
    scan_reduce<<<NB, blk, 0, stream>>>(cnt, bsum, M);
    scan_blocksums<<<1, 512, 0, stream>>>(bsum, NB);
    scan_final<<<NB, blk, 0, stream>>>(cnt, bsum, off, cur, M);
    order_kernel<<<(E + 255) / 256, blk, 0, stream>>>(ei, cur, ssrc, E);
    agg_kernel<<<(M * 64 + 255) / 256, blk, 0, stream>>>(h, off, ssrc, hpg, M);

    // ---- conv MLP: t = relu-MLP(hpg); hpg' = h + t (residual) ----
    for (int m0 = 0; m0 < M; m0 += CH) {
        const int cm = (M - m0 < CH) ? (M - m0) : CH;
        gemm_kernel<true, false><<<dim3(mtiles(cm), 4), blk, 0, stream>>>(
            hpg + (size_t)m0 * 256, conv_w1, conv_b1, nullptr, t1, cm, 256, 512);
        gemm_kernel<true, false><<<dim3(mtiles(cm), 4), blk, 0, stream>>>(
            t1, conv_w2, conv_b2, nullptr, t2, cm, 512, 512);
        gemm_kernel<true, true><<<dim3(mtiles(cm), 2), blk, 0, stream>>>(
            t2, conv_w3, conv_b3, h + (size_t)m0 * 256, hpg + (size_t)m0 * 256, cm, 512, 256);
    }

    // ---- decoder: hpg ->(relu) t1 ->(relu) t2 -> out ----
    for (int m0 = 0; m0 < M; m0 += CH) {
        const int cm = (M - m0 < CH) ? (M - m0) : CH;
        gemm_kernel<true, false><<<dim3(mtiles(cm), 4), blk, 0, stream>>>(
            hpg + (size_t)m0 * 256, dec_w1, dec_b1, nullptr, t1, cm, 256, 512);
        gemm_kernel<true, false><<<dim3(mtiles(cm), 4), blk, 0, stream>>>(
            t1, dec_w2, dec_b2, nullptr, t2, cm, 512, 512);
        gemm_kernel<false, false><<<dim3(mtiles(cm), 1), blk, 0, stream>>>(
            t2, dec_w3, dec_b3, nullptr, out + (size_t)m0 * 128, cm, 512, 128);
    }
}

// Round 3
// 1029.651 us; speedup vs baseline: 10.1876x; 5.5797x over previous
//
#include <hip/hip_runtime.h>
#include <cstdint>
#include <cstddef>

// ---------------------------------------------------------------------------
// GIN forward, bf16-MFMA edition.
// enc MLP -> CSR gather-agg -> conv MLP(+res) -> dec MLP.
// GEMMs: 128x128 tile, 4 waves, BK=64, mfma_f32_16x16x32_bf16,
// global_load_lds 16B staging (m97 structure). Activations bf16, accum fp32.
// ---------------------------------------------------------------------------

typedef __attribute__((ext_vector_type(8))) __bf16 bf16x8;
typedef __attribute__((ext_vector_type(4))) float f32x4;

__device__ __forceinline__ unsigned short f2bf(float f) {
    unsigned int u = __float_as_uint(f);
    u += 0x7FFF + ((u >> 16) & 1);          // RNE
    return (unsigned short)(u >> 16);
}
__device__ __forceinline__ float bf2f(unsigned int s) {
    return __uint_as_float(s << 16);
}

// ---------------------------- bf16 MFMA GEMM --------------------------------
// C[M,N] = epilogue(A[M,K](bf16) @ W[K,N]) with W given transposed: Wt[N,K].
// epilogue: +bias (f32), optional relu, optional +Res(bf16), store f32/bf16.
template<bool RELU, bool HAS_RES, bool SF32, bool SB16>
__global__ __launch_bounds__(256, 2)
void gemm_bf16(const unsigned short* __restrict__ A,
               const unsigned short* __restrict__ Wt,
               const float* __restrict__ Bias,
               const unsigned short* __restrict__ Res,
               float* __restrict__ Cf, unsigned short* __restrict__ Cb,
               int M, int K, int N)
{
    __shared__ unsigned short As[128 * 64];   // [row 0..127][k 0..63]
    __shared__ unsigned short Bs[128 * 64];   // [n   0..127][k 0..63]

    const int tid  = threadIdx.x;
    const int wave = tid >> 6;
    const int lane = tid & 63;
    const int m0 = blockIdx.x * 128;
    const int n0 = blockIdx.y * 128;
    const int wm = wave >> 1;                 // 0..1  (64-row half)
    const int wn = wave & 1;                  // 0..1  (64-col half)

    f32x4 acc[4][4];
#pragma unroll
    for (int i = 0; i < 4; ++i)
#pragma unroll
        for (int j = 0; j < 4; ++j) acc[i][j] = (f32x4){0.f, 0.f, 0.f, 0.f};

    // staging geometry: chunk = 1KB (64 lanes x 16B) = 8 rows of 128B
    const int srow = (wave << 5) + (lane >> 3);        // + i*8
    const int scol = (lane & 7) << 3;                  // element col (8 bf16 = 16B)

    for (int k0 = 0; k0 < K; k0 += 64) {
#pragma unroll
        for (int i = 0; i < 4; ++i) {
            const int row = srow + i * 8;
            int gm = m0 + row; gm = (gm < M) ? gm : (M - 1);   // tail clamp
            const unsigned short* gp = A + (size_t)gm * K + k0 + scol;
            __builtin_amdgcn_global_load_lds(
                (const __attribute__((address_space(1))) void*)gp,
                (__attribute__((address_space(3))) void*)&As[(wave * 2048) + i * 512],
                16, 0, 0);
        }
#pragma unroll
        for (int i = 0; i < 4; ++i) {
            const int row = srow + i * 8;
            const unsigned short* gp = Wt + (size_t)(n0 + row) * K + k0 + scol;
            __builtin_amdgcn_global_load_lds(
                (const __attribute__((address_space(1))) void*)gp,
                (__attribute__((address_space(3))) void*)&Bs[(wave * 2048) + i * 512],
                16, 0, 0);
        }
        asm volatile("s_waitcnt vmcnt(0)" ::: "memory");
        __syncthreads();

        const int lr = lane & 15;
        const int lk = (lane >> 4) << 3;
#pragma unroll
        for (int kk = 0; kk < 64; kk += 32) {
            bf16x8 af[4], bg[4];
#pragma unroll
            for (int f = 0; f < 4; ++f) {
                af[f] = *(const bf16x8*)&As[(wm * 64 + f * 16 + lr) * 64 + kk + lk];
                bg[f] = *(const bf16x8*)&Bs[(wn * 64 + f * 16 + lr) * 64 + kk + lk];
            }
#pragma unroll
            for (int mf = 0; mf < 4; ++mf)
#pragma unroll
                for (int nf = 0; nf < 4; ++nf)
                    acc[mf][nf] = __builtin_amdgcn_mfma_f32_16x16x32_bf16(
                        af[mf], bg[nf], acc[mf][nf], 0, 0, 0);
        }
        __syncthreads();
    }

    // epilogue: C/D layout col=lane&15, row=(lane>>4)*4+reg  [m89/m91]
    const int lr = lane & 15;
    const int lg = lane >> 4;
#pragma unroll
    for (int mf = 0; mf < 4; ++mf) {
#pragma unroll
        for (int r = 0; r < 4; ++r) {
            const int row = m0 + wm * 64 + mf * 16 + lg * 4 + r;
            if (row >= M) continue;
#pragma unroll
            for (int nf = 0; nf < 4; ++nf) {
                const int col = n0 + wn * 64 + nf * 16 + lr;
                float v = acc[mf][nf][r] + Bias[col];
                if (RELU) v = fmaxf(v, 0.f);
                if (HAS_RES) v += bf2f(Res[(size_t)row * N + col]);
                if (SF32) Cf[(size_t)row * N + col] = v;
                if (SB16) Cb[(size_t)row * N + col] = f2bf(v);
            }
        }
    }
}

// ----------------------- weight convert + transpose -------------------------
__global__ __launch_bounds__(256)
void wt_kernel(const float* __restrict__ W, unsigned short* __restrict__ Wt,
               int K, int N)
{
    const int idx = blockIdx.x * 256 + threadIdx.x;
    if (idx >= K * N) return;
    const int k = idx / N, n = idx - k * N;
    Wt[(size_t)n * K + k] = f2bf(W[idx]);
}

__global__ __launch_bounds__(256)
void cvt4_kernel(const float* __restrict__ in, unsigned short* __restrict__ out, int n4)
{
    const int i = blockIdx.x * 256 + threadIdx.x;
    if (i >= n4) return;
    const float4 v = ((const float4*)in)[i];
    ushort4 o;
    o.x = f2bf(v.x); o.y = f2bf(v.y); o.z = f2bf(v.z); o.w = f2bf(v.w);
    ((ushort4*)out)[i] = o;
}

// ------------------------- CSR build (counting sort) ------------------------
__global__ __launch_bounds__(256)
void zero_ints(int* __restrict__ p, int n)
{
    const int i = blockIdx.x * 256 + threadIdx.x;
    if (i < n) p[i] = 0;
}

__global__ __launch_bounds__(256)
void hist_kernel(const int* __restrict__ ei, int* __restrict__ cnt, int E)
{
    const int e = blockIdx.x * 256 + threadIdx.x;
    if (e < E) atomicAdd(&cnt[ei[E + e]], 1);
}

__global__ __launch_bounds__(256)
void scan_reduce(const int* __restrict__ cnt, int* __restrict__ bsum, int N)
{
    __shared__ int s[256];
    const int i = blockIdx.x * 256 + threadIdx.x;
    s[threadIdx.x] = (i < N) ? cnt[i] : 0;
    __syncthreads();
#pragma unroll
    for (int off = 128; off > 0; off >>= 1) {
        if (threadIdx.x < off) s[threadIdx.x] += s[threadIdx.x + off];
        __syncthreads();
    }
    if (threadIdx.x == 0) bsum[blockIdx.x] = s[0];
}

__global__ __launch_bounds__(512)
void scan_blocksums(int* __restrict__ bsum, int NB)
{
    __shared__ int a[512], b[512];
    const int t = threadIdx.x;
    const int v = (t < NB) ? bsum[t] : 0;
    a[t] = v;
    __syncthreads();
    int* s = a; int* d = b;
    for (int off = 1; off < 512; off <<= 1) {
        int x = s[t];
        if (t >= off) x += s[t - off];
        d[t] = x;
        __syncthreads();
        int* tmp = s; s = d; d = tmp;
    }
    if (t < NB) bsum[t] = s[t] - v;
}

__global__ __launch_bounds__(256)
void scan_final(const int* __restrict__ cnt, const int* __restrict__ bpre,
                int* __restrict__ off, int* __restrict__ cur, int N)
{
    __shared__ int a[256], b[256];
    const int i = blockIdx.x * 256 + threadIdx.x;
    const int t = threadIdx.x;
    const int v = (i < N) ? cnt[i] : 0;
    a[t] = v;
    __syncthreads();
    int* s = a; int* d = b;
    for (int o = 1; o < 256; o <<= 1) {
        int x = s[t];
        if (t >= o) x += s[t - o];
        d[t] = x;
        __syncthreads();
        int* tmp = s; s = d; d = tmp;
    }
    const int excl = s[t] - v + bpre[blockIdx.x];
    if (i < N) {
        off[i] = excl;
        cur[i] = excl;
        if (i == N - 1) off[N] = excl + v;
    }
}

__global__ __launch_bounds__(256)
void order_kernel(const int* __restrict__ ei, int* __restrict__ cur,
                  int* __restrict__ ssrc, int E)
{
    const int e = blockIdx.x * 256 + threadIdx.x;
    if (e >= E) return;
    const int s = ei[e];
    const int d = ei[E + e];
    const int pos = atomicAdd(&cur[d], 1);
    ssrc[pos] = s;
}

// one wave per node: hpg[i] = h[i] + sum h[src]   (bf16 in, fp32 acc, bf16 out)
__global__ __launch_bounds__(256)
void agg_kernel(const unsigned short* __restrict__ hbf, const int* __restrict__ off,
                const int* __restrict__ ssrc, unsigned short* __restrict__ hpg, int Nn)
{
    const int wid  = (int)((blockIdx.x * 256 + threadIdx.x) >> 6);
    const int lane = threadIdx.x & 63;
    if (wid >= Nn) return;
    const int e0 = off[wid], e1 = off[wid + 1];
    const uint2* base = (const uint2*)hbf;            // 4 bf16 / uint2, 64/row

    uint2 u = base[(size_t)wid * 64 + lane];
    float a0 = bf2f(u.x & 0xffffu), a1 = bf2f(u.x >> 16);
    float a2 = bf2f(u.y & 0xffffu), a3 = bf2f(u.y >> 16);

    int e = e0;
    for (; e + 1 < e1; e += 2) {
        const uint2 v0 = base[(size_t)ssrc[e] * 64 + lane];
        const uint2 v1 = base[(size_t)ssrc[e + 1] * 64 + lane];
        a0 += bf2f(v0.x & 0xffffu) + bf2f(v1.x & 0xffffu);
        a1 += bf2f(v0.x >> 16)     + bf2f(v1.x >> 16);
        a2 += bf2f(v0.y & 0xffffu) + bf2f(v1.y & 0xffffu);
        a3 += bf2f(v0.y >> 16)     + bf2f(v1.y >> 16);
    }
    if (e < e1) {
        const uint2 v0 = base[(size_t)ssrc[e] * 64 + lane];
        a0 += bf2f(v0.x & 0xffffu); a1 += bf2f(v0.x >> 16);
        a2 += bf2f(v0.y & 0xffffu); a3 += bf2f(v0.y >> 16);
    }
    uint2 o;
    o.x = (unsigned)f2bf(a0) | ((unsigned)f2bf(a1) << 16);
    o.y = (unsigned)f2bf(a2) | ((unsigned)f2bf(a3) << 16);
    ((uint2*)hpg)[(size_t)wid * 64 + lane] = o;
}

// ---------------------------------------------------------------------------

extern "C" void kernel_launch(void* const* d_in, const int* in_sizes, int n_in,
                              void* d_out, int out_size, void* d_ws, size_t ws_size,
                              hipStream_t stream)
{
    const float* x  = (const float*)d_in[0];
    const int*   ei = (const int*)d_in[1];
    const float* W[9]  = {(const float*)d_in[3],  (const float*)d_in[5],  (const float*)d_in[7],
                          (const float*)d_in[9],  (const float*)d_in[11], (const float*)d_in[13],
                          (const float*)d_in[15], (const float*)d_in[17], (const float*)d_in[19]};
    const float* B[9]  = {(const float*)d_in[4],  (const float*)d_in[6],  (const float*)d_in[8],
                          (const float*)d_in[10], (const float*)d_in[12], (const float*)d_in[14],
                          (const float*)d_in[16], (const float*)d_in[18], (const float*)d_in[20]};
    const int    Kd[9] = {128, 512, 512, 256, 512, 512, 256, 512, 512};
    const int    Nd[9] = {512, 512, 256, 512, 512, 256, 512, 512, 128};
    float* out = (float*)d_out;

    const int M = 100000;
    const int E = 1600000;
    const size_t HN = (size_t)M * 256;

    // ---- carve workspace (256B-aligned blocks) ----
    char* p = (char*)d_ws;
    auto carve = [&](size_t bytes) -> char* {
        char* r = p;
        p += (bytes + 255) & ~(size_t)255;
        return r;
    };
    unsigned short* hbf   = (unsigned short*)carve(HN * 2);          // enc out
    unsigned short* hpgbf = (unsigned short*)carve(HN * 2);          // agg out, then conv out
    unsigned short* xbf   = (unsigned short*)carve((size_t)M * 128 * 2);
    unsigned short* Wt[9];
    for (int i = 0; i < 9; ++i) Wt[i] = (unsigned short*)carve((size_t)Kd[i] * Nd[i] * 2);
    int* cnt  = (int*)carve(M * 4);
    int* off  = (int*)carve((M + 4) * 4);
    int* cur  = (int*)carve(M * 4);
    int* bsum = (int*)carve(512 * 4);
    int* ssrc = (int*)carve((size_t)E * 4);

    const size_t fixed = (size_t)(p - (char*)d_ws);
    size_t remain = (ws_size > fixed) ? ws_size - fixed : 0;
    long long ch = (long long)(remain / (2 * 512 * 2 + 64));         // t1+t2 bytes/row
    if (ch > M) ch = M;
    ch &= ~127LL;
    if (ch < 128) ch = 128;
    const int CH = (int)ch;
    unsigned short* t1 = (unsigned short*)carve((size_t)CH * 512 * 2);
    unsigned short* t2 = (unsigned short*)carve((size_t)CH * 512 * 2);

    const dim3 blk(256);
    auto mt = [](int m) { return (m + 127) / 128; };
    const int NB = (M + 255) / 256;

    // ---- weight transpose+convert, x convert, CSR build ----
    for (int i = 0; i < 9; ++i) {
        const int tot = Kd[i] * Nd[i];
        wt_kernel<<<(tot + 255) / 256, blk, 0, stream>>>(W[i], Wt[i], Kd[i], Nd[i]);
    }
    cvt4_kernel<<<(M * 128 / 4 + 255) / 256, blk, 0, stream>>>(x, xbf, M * 128 / 4);
    zero_ints<<<(M + 255) / 256, blk, 0, stream>>>(cnt, M);
    hist_kernel<<<(E + 255) / 256, blk, 0, stream>>>(ei, cnt, E);
    scan_reduce<<<NB, blk, 0, stream>>>(cnt, bsum, M);
    scan_blocksums<<<1, 512, 0, stream>>>(bsum, NB);
    scan_final<<<NB, blk, 0, stream>>>(cnt, bsum, off, cur, M);
    order_kernel<<<(E + 255) / 256, blk, 0, stream>>>(ei, cur, ssrc, E);

    // ---- encoder ----
    for (int m0 = 0; m0 < M; m0 += CH) {
        const int cm = (M - m0 < CH) ? (M - m0) : CH;
        gemm_bf16<true, false, false, true><<<dim3(mt(cm), 4), blk, 0, stream>>>(
            xbf + (size_t)m0 * 128, Wt[0], B[0], nullptr, nullptr, t1, cm, 128, 512);
        gemm_bf16<true, false, false, true><<<dim3(mt(cm), 4), blk, 0, stream>>>(
            t1, Wt[1], B[1], nullptr, nullptr, t2, cm, 512, 512);
        gemm_bf16<true, false, false, true><<<dim3(mt(cm), 2), blk, 0, stream>>>(
            t2, Wt[2], B[2], nullptr, nullptr, hbf + (size_t)m0 * 256, cm, 512, 256);
    }

    // ---- aggregation: hpg = h + sum_{src->i} h[src] ----
    agg_kernel<<<((size_t)M * 64 + 255) / 256, blk, 0, stream>>>(hbf, off, ssrc, hpgbf, M);

    // ---- conv MLP (+ residual h) ----
    for (int m0 = 0; m0 < M; m0 += CH) {
        const int cm = (M - m0 < CH) ? (M - m0) : CH;
        gemm_bf16<true, false, false, true><<<dim3(mt(cm), 4), blk, 0, stream>>>(
            hpgbf + (size_t)m0 * 256, Wt[3], B[3], nullptr, nullptr, t1, cm, 256, 512);
        gemm_bf16<true, false, false, true><<<dim3(mt(cm), 4), blk, 0, stream>>>(
            t1, Wt[4], B[4], nullptr, nullptr, t2, cm, 512, 512);
        gemm_bf16<true, true, false, true><<<dim3(mt(cm), 2), blk, 0, stream>>>(
            t2, Wt[5], B[5], hbf + (size_t)m0 * 256, nullptr, hpgbf + (size_t)m0 * 256, cm, 512, 256);
    }

    // ---- decoder ----
    for (int m0 = 0; m0 < M; m0 += CH) {
        const int cm = (M - m0 < CH) ? (M - m0) : CH;
        gemm_bf16<true, false, false, true><<<dim3(mt(cm), 4), blk, 0, stream>>>(
            hpgbf + (size_t)m0 * 256, Wt[6], B[6], nullptr, nullptr, t1, cm, 256, 512);
        gemm_bf16<true, false, false, true><<<dim3(mt(cm), 4), blk, 0, stream>>>(
            t1, Wt[7], B[7], nullptr, nullptr, t2, cm, 512, 512);
        gemm_bf16<false, false, true, false><<<dim3(mt(cm), 1), blk, 0, stream>>>(
            t2, Wt[8], B[8], nullptr, out + (size_t)m0 * 128, nullptr, cm, 512, 128);
    }
}